// Round 2
// baseline (91.815 us; speedup 1.0000x reference)
//
#include <hip/hip_runtime.h>

// Problem constants (fixed by setup_inputs)
#define BB 2
#define CC 32
#define HH 128
#define WW 256
#define DD 48
#define HW (HH * WW)      // 32768
#define NS 65             // shifts 0..64 (disp in [0,64))
#define PAD 64            // front zero pad of y rows in LDS
#define YROW (PAD + WW)   // 320

// cost[b,d,h,w] = (1/C) * sum_c x[b,c,h,w] * lerp(y[b,c,h,w-s0], y[b,c,h,w-s0+1])
// Factored: corr[s][w] = sum_c x[c,w]*ypad[c][w-s];  out = ((1-fx)*corr[s0] + fx*corr[s0-1])/C
// s0 = ceil(disp), fx = s0 - disp.
//
// Round-1 lesson: 1024-thread block => hard 128-VGPR cap. Keep phase-2
// per-thread state ~40 regs (4 shifts/wave, unroll 2) to avoid scratch spills.

__global__ __launch_bounds__(1024) void cost_volume_kernel(
    const float* __restrict__ x, const float* __restrict__ y,
    const float* __restrict__ disp, float* __restrict__ out) {
  __shared__ float xs[CC * WW];       //  32 KB
  __shared__ float ys[CC * YROW];     //  40 KB (first PAD floats of each row = 0)
  __shared__ float corr[NS * WW];     //  65 KB

  const int bx = blockIdx.x;
  const int b = bx >> 7;   // / HH
  const int h = bx & 127;
  const int tid = threadIdx.x;

  // ---------------- Phase 1: stage x row and zero-padded y row ----------------
  const int gbase = (b * CC * HH + h) * WW;  // + c*HW + w
  if (tid < 512) {  // zero the pad: 32 rows * 64 floats = 2048 floats = 512 f4
    int c = tid >> 4;
    int j = (tid & 15) << 2;
    *(float4*)&ys[c * YROW + j] = make_float4(0.f, 0.f, 0.f, 0.f);
  }
#pragma unroll
  for (int k = 0; k < 2; ++k) {
    int t = tid + (k << 10);       // 0..2047
    int c = t >> 6;                // 64 float4 per row
    int w = (t & 63) << 2;
    float4 vx = *(const float4*)(x + gbase + c * HW + w);
    float4 vy = *(const float4*)(y + gbase + c * HW + w);
    *(float4*)&xs[c * WW + w] = vx;
    *(float4*)&ys[c * YROW + PAD + w] = vy;
  }

  // Prefetch disp into registers (independent of LDS; hides phase-3 latency)
  const float* dbase = disp + (b * DD * HH + h) * WW;  // + d*HW + w
  float dvp[(DD * WW) / 1024];  // 12
#pragma unroll
  for (int k = 0; k < (DD * WW) / 1024; ++k) {
    int idx = tid + (k << 10);
    dvp[k] = dbase[(idx >> 8) * HW + (idx & 255)];
  }
  __syncthreads();

  // ---------------- Phase 2: corr[s][w] = sum_c xs[c][w] * ypad[c][w-s] -------
  // wave `wid` owns shifts [4*wid, 4*wid+3]; wave 15 additionally owns s=64.
  const int wid = tid >> 6;
  const int lane = tid & 63;
  const int w0 = lane << 2;       // each lane owns 4 consecutive w
  const int sbase = wid << 2;

  float acc[4][4];
#pragma unroll
  for (int sl = 0; sl < 4; ++sl)
#pragma unroll
    for (int wj = 0; wj < 4; ++wj) acc[sl][wj] = 0.f;
  float a64[4] = {0.f, 0.f, 0.f, 0.f};

  // window: need ypad[base-3 .. base+3], base = PAD + w0 - sbase (mult of 4).
  const int A = PAD + w0 - sbase - 4;  // >= 64 - 60 - 4 = 0; A+7 <= 319
#pragma unroll 2
  for (int c = 0; c < CC; ++c) {
    const float* yrow = &ys[c * YROW];
    float4 xv = *(const float4*)&xs[c * WW + w0];
    float4 wv0 = *(const float4*)&yrow[A];
    float4 wv1 = *(const float4*)&yrow[A + 4];
    float win[8] = {wv0.x, wv0.y, wv0.z, wv0.w, wv1.x, wv1.y, wv1.z, wv1.w};
    float xr[4] = {xv.x, xv.y, xv.z, xv.w};
#pragma unroll
    for (int sl = 0; sl < 4; ++sl)
#pragma unroll
      for (int wj = 0; wj < 4; ++wj)
        acc[sl][wj] = fmaf(xr[wj], win[4 + wj - sl], acc[sl][wj]);
    if (wid == 15) {  // s = 64: ypad index PAD + w - 64 = w0 + wj
      float4 yv = *(const float4*)&yrow[w0];
      a64[0] = fmaf(xr[0], yv.x, a64[0]);
      a64[1] = fmaf(xr[1], yv.y, a64[1]);
      a64[2] = fmaf(xr[2], yv.z, a64[2]);
      a64[3] = fmaf(xr[3], yv.w, a64[3]);
    }
  }
#pragma unroll
  for (int sl = 0; sl < 4; ++sl)
    *(float4*)&corr[(sbase + sl) * WW + w0] =
        make_float4(acc[sl][0], acc[sl][1], acc[sl][2], acc[sl][3]);
  if (wid == 15)
    *(float4*)&corr[64 * WW + w0] = make_float4(a64[0], a64[1], a64[2], a64[3]);
  __syncthreads();

  // ---------------- Phase 3: per-output lerp over corr ------------------------
  const float inv_c = 1.0f / (float)CC;
  float* obase = out + (b * DD * HH + h) * WW;
#pragma unroll
  for (int k = 0; k < (DD * WW) / 1024; ++k) {  // 12 iters
    int idx = tid + (k << 10);
    int d = idx >> 8;   // / WW
    int w = idx & 255;
    float dv = dvp[k];
    float s0f = ceilf(dv);
    int i0 = (int)s0f;
    float fx = s0f - dv;             // in [0,1)
    int i1 = (i0 > 0) ? i0 - 1 : 0;  // i0==0 => fx==0, weight-0 read
    float c0 = corr[i0 * WW + w];    // lanes vary w: stride-256 rows => conflict-free
    float c1 = corr[i1 * WW + w];
    obase[d * HW + w] = (c0 + fx * (c1 - c0)) * inv_c;
  }
}

extern "C" void kernel_launch(void* const* d_in, const int* in_sizes, int n_in,
                              void* d_out, int out_size, void* d_ws, size_t ws_size,
                              hipStream_t stream) {
  const float* x = (const float*)d_in[0];
  const float* y = (const float*)d_in[1];
  const float* disp = (const float*)d_in[2];
  float* out = (float*)d_out;
  cost_volume_kernel<<<BB * HH, 1024, 0, stream>>>(x, y, disp, out);
}

// Round 3
// 89.551 us; speedup vs baseline: 1.0253x; 1.0253x over previous
//
#include <hip/hip_runtime.h>

// Problem constants (fixed by setup_inputs)
#define BB 2
#define CC 32
#define HH 128
#define WW 256
#define DD 48
#define HW (HH * WW)      // 32768
#define NS 65             // shifts 0..64 (disp in [0,64))
#define PAD 64            // front zero pad of y rows in LDS
#define YROW (PAD + WW)   // 320
#define NT 512            // 8 waves

// cost[b,d,h,w] = (1/C) * sum_c x[b,c,h,w] * lerp(y[b,c,h,w-s0], y[b,c,h,w-s0+1])
// Factored: corr[s][w] = sum_c x[c,w]*ypad[c][w-s];  out = ((1-fx)*corr[s0] + fx*corr[s0-1])/C
// s0 = ceil(disp), fx = s0 - disp.
//
// Round-2 lesson: phase-2 LDS issue dominates. Window traffic scales as
// (cols_per_lane + shifts_per_wave), so 8 shifts/wave halves wave-level
// ds_read_b128 count vs 4 shifts/wave at the same 4 cols/lane.
// 512 threads => 2 waves/SIMD at 1 block/CU => 256-VGPR budget, no spills.

__global__ __launch_bounds__(NT) void cost_volume_kernel(
    const float* __restrict__ x, const float* __restrict__ y,
    const float* __restrict__ disp, float* __restrict__ out) {
  __shared__ float xs[CC * WW];       //  32 KB
  __shared__ float ys[CC * YROW];     //  40 KB (first PAD floats of each row = 0)
  __shared__ float corr[NS * WW];     //  65 KB

  const int bx = blockIdx.x;
  const int b = bx >> 7;   // / HH
  const int h = bx & 127;
  const int tid = threadIdx.x;

  // ---------------- Phase 1: stage x row and zero-padded y row ----------------
  const int gbase = (b * CC * HH + h) * WW;  // + c*HW + w
  {  // zero the pad: 32 rows * 64 floats = 2048 floats = 512 float4 (1/thread)
    int c = tid >> 4;
    int j = (tid & 15) << 2;
    *(float4*)&ys[c * YROW + j] = make_float4(0.f, 0.f, 0.f, 0.f);
  }
#pragma unroll
  for (int k = 0; k < 4; ++k) {
    int t = tid + (k << 9);        // 0..2047
    int c = t >> 6;                // 64 float4 per row
    int w = (t & 63) << 2;
    float4 vx = *(const float4*)(x + gbase + c * HW + w);
    float4 vy = *(const float4*)(y + gbase + c * HW + w);
    *(float4*)&xs[c * WW + w] = vx;
    *(float4*)&ys[c * YROW + PAD + w] = vy;
  }
  __syncthreads();

  // ---------------- Phase 2: corr[s][w] = sum_c xs[c][w] * ypad[c][w-s] -------
  // wave `wid` owns shifts [8*wid, 8*wid+7]; wave 7 additionally owns s=64.
  const int wid = tid >> 6;
  const int lane = tid & 63;
  const int w0 = lane << 2;       // each lane owns 4 consecutive w
  const int sbase = wid << 3;

  float acc[8][4];
#pragma unroll
  for (int sl = 0; sl < 8; ++sl)
#pragma unroll
    for (int wj = 0; wj < 4; ++wj) acc[sl][wj] = 0.f;
  float a64[4] = {0.f, 0.f, 0.f, 0.f};

  // window needed: ypad[A+1 .. A+11], A = PAD + w0 - sbase - 8 (mult of 4).
  // wid=7: A = w0 >= 0; wid=0: A = 56+w0 <= 308, A+11 <= 319.  In bounds.
  const int A = PAD + w0 - sbase - 8;
#pragma unroll 2
  for (int c = 0; c < CC; ++c) {
    const float* yrow = &ys[c * YROW];
    float4 xv = *(const float4*)&xs[c * WW + w0];
    float4 wv0 = *(const float4*)&yrow[A];
    float4 wv1 = *(const float4*)&yrow[A + 4];
    float4 wv2 = *(const float4*)&yrow[A + 8];
    float win[12] = {wv0.x, wv0.y, wv0.z, wv0.w, wv1.x, wv1.y,
                     wv1.z, wv1.w, wv2.x, wv2.y, wv2.z, wv2.w};
    float xr[4] = {xv.x, xv.y, xv.z, xv.w};
#pragma unroll
    for (int sl = 0; sl < 8; ++sl)
#pragma unroll
      for (int wj = 0; wj < 4; ++wj)
        acc[sl][wj] = fmaf(xr[wj], win[8 + wj - sl], acc[sl][wj]);
    if (wid == 7) {  // s = 64: ypad index PAD + w - 64 = w0 + wj
      float4 yv = *(const float4*)&yrow[w0];
      a64[0] = fmaf(xr[0], yv.x, a64[0]);
      a64[1] = fmaf(xr[1], yv.y, a64[1]);
      a64[2] = fmaf(xr[2], yv.z, a64[2]);
      a64[3] = fmaf(xr[3], yv.w, a64[3]);
    }
  }
#pragma unroll
  for (int sl = 0; sl < 8; ++sl)
    *(float4*)&corr[(sbase + sl) * WW + w0] =
        make_float4(acc[sl][0], acc[sl][1], acc[sl][2], acc[sl][3]);
  if (wid == 7)
    *(float4*)&corr[64 * WW + w0] = make_float4(a64[0], a64[1], a64[2], a64[3]);
  __syncthreads();

  // ---------------- Phase 3: per-output lerp over corr ------------------------
  const float inv_c = 1.0f / (float)CC;
  const float* dbase = disp + (b * DD * HH + h) * WW;  // + d*HW + w
  float* obase = out + (b * DD * HH + h) * WW;
#pragma unroll 4
  for (int k = 0; k < (DD * WW) / NT; ++k) {  // 24 iters
    int idx = tid + (k << 9);
    int d = idx >> 8;   // / WW
    int w = idx & 255;
    float dv = dbase[d * HW + w];
    float s0f = ceilf(dv);
    int i0 = (int)s0f;
    float fx = s0f - dv;             // in [0,1)
    int i1 = (i0 > 0) ? i0 - 1 : 0;  // i0==0 => fx==0, weight-0 read
    float c0 = corr[i0 * WW + w];    // lanes vary w; row stride 256 ≡ 0 mod 32 => conflict-free
    float c1 = corr[i1 * WW + w];
    obase[d * HW + w] = (c0 + fx * (c1 - c0)) * inv_c;
  }
}

extern "C" void kernel_launch(void* const* d_in, const int* in_sizes, int n_in,
                              void* d_out, int out_size, void* d_ws, size_t ws_size,
                              hipStream_t stream) {
  const float* x = (const float*)d_in[0];
  const float* y = (const float*)d_in[1];
  const float* disp = (const float*)d_in[2];
  float* out = (float*)d_out;
  cost_volume_kernel<<<BB * HH, NT, 0, stream>>>(x, y, disp, out);
}

// Round 4
// 89.229 us; speedup vs baseline: 1.0290x; 1.0036x over previous
//
#include <hip/hip_runtime.h>

// Problem constants (fixed by setup_inputs)
#define BB 2
#define CC 32
#define HH 128
#define WW 256
#define DD 48
#define HW (HH * WW)      // 32768
#define NS 65             // shifts 0..64 (disp in [0,64))
#define PAD 64            // front zero pad of y rows in LDS
#define YROW (PAD + WW)   // 320
#define NT 512            // 8 waves

// cost[b,d,h,w] = (1/C) * sum_c x[b,c,h,w] * lerp(y[b,c,h,w-s0], y[b,c,h,w-s0+1])
// Factored: corr[s][w] = sum_c x[c,w]*ypad[c][w-s];  out = ((1-fx)*corr[s0] + fx*corr[s0-1])/C
// s0 = ceil(disp), fx = s0 - disp.
//
// Round-3 lesson: dur_us is ~75% harness restore/poison floor; kernel < 42 us.
// This round: x read from global (L1) instead of LDS (VMEM || LDS pipes),
// disp prefetched to regs during phase 1, float4 epilogue.

__global__ __launch_bounds__(NT) void cost_volume_kernel(
    const float* __restrict__ x, const float* __restrict__ y,
    const float* __restrict__ disp, float* __restrict__ out) {
  __shared__ float ys[CC * YROW];     //  40 KB (first PAD floats of each row = 0)
  __shared__ float corr[NS * WW];     //  65 KB

  const int bx = blockIdx.x;
  const int b = bx >> 7;   // / HH
  const int h = bx & 127;
  const int tid = threadIdx.x;

  const int gbase = (b * CC * HH + h) * WW;  // + c*HW + w

  // ---------------- Phase 1: stage zero-padded y row; prefetch disp ----------
  {  // zero the pad: 32 rows * 64 floats = 2048 floats = 512 float4 (1/thread)
    int c = tid >> 4;
    int j = (tid & 15) << 2;
    *(float4*)&ys[c * YROW + j] = make_float4(0.f, 0.f, 0.f, 0.f);
  }
#pragma unroll
  for (int k = 0; k < 4; ++k) {
    int t = tid + (k << 9);        // 0..2047
    int c = t >> 6;                // 64 float4 per row
    int w = (t & 63) << 2;
    *(float4*)&ys[c * YROW + PAD + w] = *(const float4*)(y + gbase + c * HW + w);
  }
  // disp prefetch: 6 float4/thread; completes under the barrier's vmcnt drain,
  // overlapped with the y stores above. Removes all phase-3 load latency.
  const float* dbase = disp + (b * DD * HH + h) * WW;  // + d*HW + w
  float4 dv4[6];
#pragma unroll
  for (int j = 0; j < 6; ++j) {
    int t = tid + (j << 9);        // float4 index 0..3071
    int d = t >> 6;                // 64 float4 per w-row
    int w4 = (t & 63) << 2;
    dv4[j] = *(const float4*)(dbase + d * HW + w4);
  }
  __syncthreads();

  // ---------------- Phase 2: corr[s][w] = sum_c x[c][w] * ypad[c][w-s] -------
  // wave `wid` owns shifts [8*wid, 8*wid+7]; wave 7 additionally owns s=64.
  // x comes straight from global: all waves hit the same 32 KB row -> L1.
  const int wid = tid >> 6;
  const int lane = tid & 63;
  const int w0 = lane << 2;       // each lane owns 4 consecutive w
  const int sbase = wid << 3;

  float acc[8][4];
#pragma unroll
  for (int sl = 0; sl < 8; ++sl)
#pragma unroll
    for (int wj = 0; wj < 4; ++wj) acc[sl][wj] = 0.f;
  float a64[4] = {0.f, 0.f, 0.f, 0.f};

  // window needed: ypad[A+1 .. A+11], A = PAD + w0 - sbase - 8 (mult of 4).
  // wid=7: A = w0 >= 0; wid=0: A = 56+w0 <= 308, A+11 <= 319.  In bounds.
  const int A = PAD + w0 - sbase - 8;
  const float* xcol = x + gbase + w0;  // + c*HW
#pragma unroll 2
  for (int c = 0; c < CC; ++c) {
    const float* yrow = &ys[c * YROW];
    float4 xv = *(const float4*)(xcol + c * HW);   // global (L1), VMEM pipe
    float4 wv0 = *(const float4*)&yrow[A];
    float4 wv1 = *(const float4*)&yrow[A + 4];
    float4 wv2 = *(const float4*)&yrow[A + 8];
    float win[12] = {wv0.x, wv0.y, wv0.z, wv0.w, wv1.x, wv1.y,
                     wv1.z, wv1.w, wv2.x, wv2.y, wv2.z, wv2.w};
    float xr[4] = {xv.x, xv.y, xv.z, xv.w};
#pragma unroll
    for (int sl = 0; sl < 8; ++sl)
#pragma unroll
      for (int wj = 0; wj < 4; ++wj)
        acc[sl][wj] = fmaf(xr[wj], win[8 + wj - sl], acc[sl][wj]);
    if (wid == 7) {  // s = 64: ypad index PAD + w - 64 = w0 + wj
      float4 yv = *(const float4*)&yrow[w0];
      a64[0] = fmaf(xr[0], yv.x, a64[0]);
      a64[1] = fmaf(xr[1], yv.y, a64[1]);
      a64[2] = fmaf(xr[2], yv.z, a64[2]);
      a64[3] = fmaf(xr[3], yv.w, a64[3]);
    }
  }
#pragma unroll
  for (int sl = 0; sl < 8; ++sl)
    *(float4*)&corr[(sbase + sl) * WW + w0] =
        make_float4(acc[sl][0], acc[sl][1], acc[sl][2], acc[sl][3]);
  if (wid == 7)
    *(float4*)&corr[64 * WW + w0] = make_float4(a64[0], a64[1], a64[2], a64[3]);
  __syncthreads();

  // ---------------- Phase 3: per-output lerp over corr, float4 epilogue ------
  const float inv_c = 1.0f / (float)CC;
  float* obase = out + (b * DD * HH + h) * WW;
#pragma unroll
  for (int j = 0; j < 6; ++j) {
    int t = tid + (j << 9);
    int d = t >> 6;
    int w4 = (t & 63) << 2;
    float dv[4] = {dv4[j].x, dv4[j].y, dv4[j].z, dv4[j].w};
    float o[4];
#pragma unroll
    for (int e = 0; e < 4; ++e) {
      float s0f = ceilf(dv[e]);
      int i0 = (int)s0f;
      float fx = s0f - dv[e];          // in [0,1)
      int i1 = (i0 > 0) ? i0 - 1 : 0;  // i0==0 => fx==0, weight-0 read
      float c0 = corr[i0 * WW + w4 + e];
      float c1 = corr[i1 * WW + w4 + e];
      o[e] = (c0 + fx * (c1 - c0)) * inv_c;
    }
    *(float4*)(obase + d * HW + w4) = make_float4(o[0], o[1], o[2], o[3]);
  }
}

extern "C" void kernel_launch(void* const* d_in, const int* in_sizes, int n_in,
                              void* d_out, int out_size, void* d_ws, size_t ws_size,
                              hipStream_t stream) {
  const float* x = (const float*)d_in[0];
  const float* y = (const float*)d_in[1];
  const float* disp = (const float*)d_in[2];
  float* out = (float*)d_out;
  cost_volume_kernel<<<BB * HH, NT, 0, stream>>>(x, y, disp, out);
}